// Round 5
// baseline (159.420 us; speedup 1.0000x reference)
//
#include <hip/hip_runtime.h>
#include <math.h>

// Problem constants (fixed by the reference):
constexpr int B = 4, C = 64, N = 65536, K = 16;

// Round-to-nearest-even fp32 -> bf16 (inputs are finite normals).
__device__ __forceinline__ unsigned short f2bf(float x) {
  unsigned int u = __float_as_uint(x);
  unsigned int r = (u + 0x7FFFu + ((u >> 16) & 1u)) >> 16;
  return (unsigned short)r;
}

// ---------------------------------------------------------------------------
// Kernel 1: transpose + convert: f fp32 [B, C, N] -> ft bf16 [B, N, C].
// 64x64 tiles through padded LDS; coalesced reads; ushort2 packed stores.
// ---------------------------------------------------------------------------
__global__ __launch_bounds__(256) void transpose_bf16_kernel(
    const float* __restrict__ f, unsigned short* __restrict__ ft) {
  __shared__ float tile[64][65];
  const int n0 = blockIdx.x * 64;
  const int b  = blockIdx.y;
  const float*    fb  = f  + (size_t)b * C * N;
  unsigned short* ftb = ft + (size_t)b * N * C;
  const int tx = threadIdx.x;  // 0..63
  const int ty = threadIdx.y;  // 0..3
  const int t  = ty * 64 + tx;

#pragma unroll
  for (int i = 0; i < 64; i += 4) {
    const int c = ty + i;
    tile[c][tx] = fb[(size_t)c * N + n0 + tx];  // coalesced along n
  }
  __syncthreads();

  // Store phase: thread t -> (c-pair c2 = t&31, n = (t>>5) + 8*i).
  // LDS read banks (2*c2 + n) mod 32: 2-way per instruction -> free.
  const int c2    = t & 31;
  const int nbase = t >> 5;
#pragma unroll
  for (int i = 0; i < 64; i += 8) {
    const int n  = nbase + i;
    const float lo = tile[2 * c2][n];
    const float hi = tile[2 * c2 + 1][n];
    ushort2 pk;
    pk.x = f2bf(lo);
    pk.y = f2bf(hi);
    *reinterpret_cast<ushort2*>(&ftb[(size_t)(n0 + n) * C + 2 * c2]) = pk;
  }
}

// ---------------------------------------------------------------------------
// Kernel 2: gather-max v5 (bf16 rows; max-TLP).
// vs v4: no idx LDS staging (indices loaded straight from global — already
// coalesced 32B spans, each consumed once, nontemporal) -> LDS 33.8->17.4 KB,
// and __launch_bounds__(256,8) caps VGPR at 64 (v4 used 52) so we get
// 8 blocks/CU = 32 waves/CU (~3x the wave concurrency of v4).
// Lane (g = lane>>3, c8 = lane&7): one wave gather instr = 8 rows x 128 B.
// Per-wave private LDS chunk tile for the n<->c transpose; no __syncthreads.
// Output stores nontemporal (one-touch stream; don't evict table from L2).
// ---------------------------------------------------------------------------
__global__ __launch_bounds__(256, 8) void gather_max_v5(
    const unsigned short* __restrict__ ft, const int* __restrict__ nb,
    float* __restrict__ out) {
  __shared__ float tile[4][16][68];  // per-wave [n-chunk 16][c 64 + pad 4]

  const int t    = threadIdx.x;
  const int wave = t >> 6;
  const int lane = t & 63;
  const int g    = lane >> 3;  // 0..7 : row within 8-row gather group
  const int c8   = lane & 7;   // channel octet: c = 8*c8 .. 8*c8+7
  const int n0   = blockIdx.x * 256;
  const int b    = blockIdx.y;

  const unsigned short* ftb  = ft  + (size_t)b * N * C;
  const int*            nbb  = nb  + (size_t)b * K * N;
  float*                outb = out + (size_t)b * C * N;

  const int wbase = wave * 64;

  for (int chunk = 0; chunk < 4; ++chunk) {  // 16 n per chunk
#pragma unroll
    for (int it = 0; it < 2; ++it) {         // 8 n per gather group
      const int n_glob = n0 + wbase + chunk * 16 + it * 8 + g;

      float acc[8];
#pragma unroll
      for (int j = 0; j < 8; ++j) acc[j] = -INFINITY;

#pragma unroll
      for (int kb = 0; kb < 2; ++kb) {  // two 8-deep load batches
        // Indices straight from global: per-instr 8 distinct consecutive
        // ints (32B span), replicated over c8 lanes; consumed once.
        int off[8];
#pragma unroll
        for (int k = 0; k < 8; ++k) {
          off[k] = __builtin_nontemporal_load(
              &nbb[(size_t)(kb * 8 + k) * N + n_glob]);
        }

        uint4 v[8];
#pragma unroll
        for (int k = 0; k < 8; ++k) {
          v[k] = *reinterpret_cast<const uint4*>(
              ftb + ((size_t)off[k] << 6) + (c8 << 3));
        }

#pragma unroll
        for (int k = 0; k < 8; ++k) {
          const unsigned int w0 = v[k].x, w1 = v[k].y, w2 = v[k].z, w3 = v[k].w;
          acc[0] = fmaxf(acc[0], __uint_as_float(w0 << 16));
          acc[1] = fmaxf(acc[1], __uint_as_float(w0 & 0xFFFF0000u));
          acc[2] = fmaxf(acc[2], __uint_as_float(w1 << 16));
          acc[3] = fmaxf(acc[3], __uint_as_float(w1 & 0xFFFF0000u));
          acc[4] = fmaxf(acc[4], __uint_as_float(w2 << 16));
          acc[5] = fmaxf(acc[5], __uint_as_float(w2 & 0xFFFF0000u));
          acc[6] = fmaxf(acc[6], __uint_as_float(w3 << 16));
          acc[7] = fmaxf(acc[7], __uint_as_float(w3 & 0xFFFF0000u));
        }
      }

      const int r = it * 8 + g;
      float4 a0 = make_float4(acc[0], acc[1], acc[2], acc[3]);
      float4 a1 = make_float4(acc[4], acc[5], acc[6], acc[7]);
      *reinterpret_cast<float4*>(&tile[wave][r][c8 * 8])     = a0;
      *reinterpret_cast<float4*>(&tile[wave][r][c8 * 8 + 4]) = a1;
    }
    // Wave-private LDS round-trip: LDS pipe is in-order per wave; fence the
    // compiler so it can't reorder the reads above the writes.
    asm volatile("s_waitcnt lgkmcnt(0)" ::: "memory");

    // Transposed store: 16 n x 64 c chunk. lane -> (n_off, c_sub);
    // each instruction stores 4 contiguous 64B segments (one per c_sub).
    const int n_off = lane & 15;
    const int c_sub = lane >> 4;
    const int n_glob = n0 + wbase + chunk * 16 + n_off;
#pragma unroll
    for (int ci = 0; ci < 16; ++ci) {
      const int c = ci * 4 + c_sub;
      // LDS read banks: (4*n_off + c_sub + 4*ci) mod 32 -> exact 2-way, free
      __builtin_nontemporal_store(tile[wave][n_off][c],
                                  &outb[(size_t)c * N + n_glob]);
    }
    asm volatile("" ::: "memory");  // keep next chunk's writes below the reads
  }
}

// ---------------------------------------------------------------------------
// Fallback (workspace too small): direct gather, correct but slow.
// ---------------------------------------------------------------------------
__global__ __launch_bounds__(256) void naive_kernel(
    const float* __restrict__ f, const int* __restrict__ nb,
    float* __restrict__ out) {
  const int n = blockIdx.x * 256 + threadIdx.x;
  const int c = blockIdx.y;
  const int b = blockIdx.z;
  if (n >= N) return;
  const float* fb  = f  + (size_t)b * C * N + (size_t)c * N;
  const int*   nbb = nb + (size_t)b * K * N;
  float acc = -INFINITY;
#pragma unroll
  for (int k = 0; k < K; ++k) {
    acc = fmaxf(acc, fb[nbb[(size_t)k * N + n]]);
  }
  out[(size_t)b * C * N + (size_t)c * N + n] = acc;
}

extern "C" void kernel_launch(void* const* d_in, const int* in_sizes, int n_in,
                              void* d_out, int out_size, void* d_ws, size_t ws_size,
                              hipStream_t stream) {
  const float* f   = (const float*)d_in[0];
  const int*   nb  = (const int*)d_in[1];
  float*       out = (float*)d_out;

  const size_t need = (size_t)B * N * C * sizeof(unsigned short);
  if (ws_size >= need) {
    unsigned short* ft = (unsigned short*)d_ws;
    transpose_bf16_kernel<<<dim3(N / 64, B), dim3(64, 4), 0, stream>>>(f, ft);
    gather_max_v5<<<dim3(N / 256, B), 256, 0, stream>>>(ft, nb, out);
  } else {
    naive_kernel<<<dim3((N + 255) / 256, C, B), 256, 0, stream>>>(f, nb, out);
  }
}

// Round 6
// 84.906 us; speedup vs baseline: 1.8776x; 1.8776x over previous
//
#include <hip/hip_runtime.h>
#include <math.h>

// Problem constants (fixed by the reference):
constexpr int B = 4, C = 64, N = 65536, K = 16;

// Round-to-nearest-even fp32 -> bf16 (inputs are finite normals).
__device__ __forceinline__ unsigned short f2bf(float x) {
  unsigned int u = __float_as_uint(x);
  unsigned int r = (u + 0x7FFFu + ((u >> 16) & 1u)) >> 16;
  return (unsigned short)r;
}

// ---------------------------------------------------------------------------
// Kernel 1: transpose + convert: f fp32 [B, C, N] -> ft bf16 [B, N, C].
// 64x64 tiles through padded LDS; coalesced reads; ushort2 packed stores.
// (Measured ~roofline: ~96 MB moved, ~16 us.)
// ---------------------------------------------------------------------------
__global__ __launch_bounds__(256) void transpose_bf16_kernel(
    const float* __restrict__ f, unsigned short* __restrict__ ft) {
  __shared__ float tile[64][65];
  const int n0 = blockIdx.x * 64;
  const int b  = blockIdx.y;
  const float*    fb  = f  + (size_t)b * C * N;
  unsigned short* ftb = ft + (size_t)b * N * C;
  const int tx = threadIdx.x;  // 0..63
  const int ty = threadIdx.y;  // 0..3
  const int t  = ty * 64 + tx;

#pragma unroll
  for (int i = 0; i < 64; i += 4) {
    const int c = ty + i;
    tile[c][tx] = fb[(size_t)c * N + n0 + tx];  // coalesced along n
  }
  __syncthreads();

  const int c2    = t & 31;
  const int nbase = t >> 5;
#pragma unroll
  for (int i = 0; i < 64; i += 8) {
    const int n  = nbase + i;
    const float lo = tile[2 * c2][n];
    const float hi = tile[2 * c2 + 1][n];
    ushort2 pk;
    pk.x = f2bf(lo);
    pk.y = f2bf(hi);
    *reinterpret_cast<ushort2*>(&ftb[(size_t)(n0 + n) * C + 2 * c2]) = pk;
  }
}

// ---------------------------------------------------------------------------
// Kernel 2: gather-max v6 — v4's structure, occupancy via geometry.
// v5 lessons: (a) grid of 1024 blocks capped us at 4 blocks/CU — LDS/VGPR
// tweaks couldn't matter; (b) (256,8) strangled VGPRs to 32; (c) nontemporal
// hints inflated FETCH (idx line reuse lost) and WRITE (partial-line stores).
// v6: block covers 64 n (4 waves x 16 n), grid = 4096 blocks. LDS = 4 KB idx
// + 17.4 KB tile = 21.4 KB -> 7 blocks/CU = 28 waves/CU (~87%). Per-wave
// load pattern identical to v4 (two 8-deep uint4 gather batches). All LDS
// traffic wave-private -> zero __syncthreads. No nontemporal anywhere.
// ---------------------------------------------------------------------------
__global__ __launch_bounds__(256, 4) void gather_max_v6(
    const unsigned short* __restrict__ ft, const int* __restrict__ nb,
    float* __restrict__ out) {
  __shared__ int   idx_s[4][K][16];  // [wave][k][n within wave's 16]
  __shared__ float tile[4][16][68];  // per-wave [n 16][c 64 + pad 4]

  const int t    = threadIdx.x;
  const int wave = t >> 6;
  const int lane = t & 63;
  const int g    = lane >> 3;  // 0..7 : row within 8-row gather group
  const int c8   = lane & 7;   // channel octet: c = 8*c8 .. 8*c8+7
  const int n0   = blockIdx.x * 64;
  const int b    = blockIdx.y;
  const int wn0  = n0 + wave * 16;  // this wave's first n

  const unsigned short* ftb  = ft  + (size_t)b * N * C;
  const int*            nbb  = nb  + (size_t)b * K * N;
  float*                outb = out + (size_t)b * C * N;

  // Wave-private idx staging: lane (kq = lane>>4, nn = lane&15); 4 loads of
  // 4x64B segments cover k = 0..15 for the wave's 16 n. No barrier needed.
  {
    const int kq = lane >> 4;
    const int nn = lane & 15;
#pragma unroll
    for (int i = 0; i < 4; ++i) {
      const int k = i * 4 + kq;
      idx_s[wave][k][nn] = nbb[(size_t)k * N + wn0 + nn];
    }
  }
  asm volatile("s_waitcnt lgkmcnt(0)" ::: "memory");

#pragma unroll
  for (int it = 0; it < 2; ++it) {  // two 8-n gather groups
    const int r = it * 8 + g;       // n offset within wave's 16

    float acc[8];
#pragma unroll
    for (int j = 0; j < 8; ++j) acc[j] = -INFINITY;

#pragma unroll
    for (int kb = 0; kb < 2; ++kb) {  // two 8-deep load batches
      int off[8];
#pragma unroll
      for (int k = 0; k < 8; ++k) off[k] = idx_s[wave][kb * 8 + k][r];

      uint4 v[8];
#pragma unroll
      for (int k = 0; k < 8; ++k) {
        v[k] = *reinterpret_cast<const uint4*>(
            ftb + ((size_t)off[k] << 6) + (c8 << 3));
      }

#pragma unroll
      for (int k = 0; k < 8; ++k) {
        const unsigned int w0 = v[k].x, w1 = v[k].y, w2 = v[k].z, w3 = v[k].w;
        acc[0] = fmaxf(acc[0], __uint_as_float(w0 << 16));
        acc[1] = fmaxf(acc[1], __uint_as_float(w0 & 0xFFFF0000u));
        acc[2] = fmaxf(acc[2], __uint_as_float(w1 << 16));
        acc[3] = fmaxf(acc[3], __uint_as_float(w1 & 0xFFFF0000u));
        acc[4] = fmaxf(acc[4], __uint_as_float(w2 << 16));
        acc[5] = fmaxf(acc[5], __uint_as_float(w2 & 0xFFFF0000u));
        acc[6] = fmaxf(acc[6], __uint_as_float(w3 << 16));
        acc[7] = fmaxf(acc[7], __uint_as_float(w3 & 0xFFFF0000u));
      }
    }

    float4 a0 = make_float4(acc[0], acc[1], acc[2], acc[3]);
    float4 a1 = make_float4(acc[4], acc[5], acc[6], acc[7]);
    *reinterpret_cast<float4*>(&tile[wave][r][c8 * 8])     = a0;
    *reinterpret_cast<float4*>(&tile[wave][r][c8 * 8 + 4]) = a1;
  }
  // Wave-private LDS round-trip; LDS in-order per wave; fence the compiler.
  asm volatile("s_waitcnt lgkmcnt(0)" ::: "memory");

  // Transposed store: 16 n x 64 c. lane -> (n_off, c_sub); each instruction
  // stores 4 contiguous 64B segments.
  const int n_off  = lane & 15;
  const int c_sub  = lane >> 4;
  const int n_glob = wn0 + n_off;
#pragma unroll
  for (int ci = 0; ci < 16; ++ci) {
    const int c = ci * 4 + c_sub;
    // LDS read banks: (4*n_off + c_sub + 4*ci) mod 32 -> exact 2-way, free
    outb[(size_t)c * N + n_glob] = tile[wave][n_off][c];
  }
}

// ---------------------------------------------------------------------------
// Fallback (workspace too small): direct gather, correct but slow.
// ---------------------------------------------------------------------------
__global__ __launch_bounds__(256) void naive_kernel(
    const float* __restrict__ f, const int* __restrict__ nb,
    float* __restrict__ out) {
  const int n = blockIdx.x * 256 + threadIdx.x;
  const int c = blockIdx.y;
  const int b = blockIdx.z;
  if (n >= N) return;
  const float* fb  = f  + (size_t)b * C * N + (size_t)c * N;
  const int*   nbb = nb + (size_t)b * K * N;
  float acc = -INFINITY;
#pragma unroll
  for (int k = 0; k < K; ++k) {
    acc = fmaxf(acc, fb[nbb[(size_t)k * N + n]]);
  }
  out[(size_t)b * C * N + (size_t)c * N + n] = acc;
}

extern "C" void kernel_launch(void* const* d_in, const int* in_sizes, int n_in,
                              void* d_out, int out_size, void* d_ws, size_t ws_size,
                              hipStream_t stream) {
  const float* f   = (const float*)d_in[0];
  const int*   nb  = (const int*)d_in[1];
  float*       out = (float*)d_out;

  const size_t need = (size_t)B * N * C * sizeof(unsigned short);
  if (ws_size >= need) {
    unsigned short* ft = (unsigned short*)d_ws;
    transpose_bf16_kernel<<<dim3(N / 64, B), dim3(64, 4), 0, stream>>>(f, ft);
    gather_max_v6<<<dim3(N / 64, B), 256, 0, stream>>>(ft, nb, out);
  } else {
    naive_kernel<<<dim3((N + 255) / 256, C, B), 256, 0, stream>>>(f, nb, out);
  }
}